// Round 6
// baseline (764.639 us; speedup 1.0000x reference)
//
#include <hip/hip_runtime.h>
#include <hip/hip_bf16.h>

#define NB 8
#define NS 1024
#define ND 1024
#define NH 16
#define NDK 64
#define NDFF 4096

typedef __bf16 bf16;
typedef __attribute__((ext_vector_type(8))) __bf16 bf16x8;
typedef __attribute__((ext_vector_type(4))) __bf16 bf16x4;
typedef __attribute__((ext_vector_type(4))) float f32x4;

__device__ __forceinline__ void gload16(const bf16* g, bf16* l) {
  __builtin_amdgcn_global_load_lds(
      (const __attribute__((address_space(1))) void*)g,
      (__attribute__((address_space(3))) void*)l, 16, 0, 0);
}

// ---- weight convert + transpose: W f32 [K][N] -> WT bf16 [N][K] ----
__global__ void wconv_t(const float* __restrict__ W, bf16* __restrict__ WT,
                        int K, int N) {
  __shared__ float tile[32][33];
  int n0 = blockIdx.x * 32, k0 = blockIdx.y * 32;
  int tx = threadIdx.x, ty = threadIdx.y;
#pragma unroll
  for (int i2 = 0; i2 < 4; ++i2) {
    int i = ty + i2 * 8;
    tile[i][tx] = W[(long)(k0 + i) * N + n0 + tx];
  }
  __syncthreads();
#pragma unroll
  for (int i2 = 0; i2 < 4; ++i2) {
    int i = ty + i2 * 8;
    WT[(long)(n0 + i) * K + k0 + tx] = (bf16)tile[tx][i];
  }
}

// ---- fused layernorm: out_ln = bf16(LN(x)), out_lnpos = bf16(LN(x)+pos) ----
__global__ void ln_fused(const float* __restrict__ in, const float* __restrict__ gam,
                         const float* __restrict__ bet, const float* __restrict__ pos,
                         bf16* __restrict__ out_ln, bf16* __restrict__ out_lnpos) {
  long row = blockIdx.x;
  int t = threadIdx.x;  // 256
  float4 v = ((const float4*)(in + row * ND))[t];
  float s = v.x + v.y + v.z + v.w;
  float s2 = v.x * v.x + v.y * v.y + v.z * v.z + v.w * v.w;
#pragma unroll
  for (int m = 32; m >= 1; m >>= 1) {
    s += __shfl_xor(s, m);
    s2 += __shfl_xor(s2, m);
  }
  __shared__ float red[8];
  if ((t & 63) == 0) {
    red[t >> 6] = s;
    red[4 + (t >> 6)] = s2;
  }
  __syncthreads();
  float ts = red[0] + red[1] + red[2] + red[3];
  float ts2 = red[4] + red[5] + red[6] + red[7];
  float mu = ts * (1.0f / ND);
  float var = ts2 * (1.0f / ND) - mu * mu;
  float rstd = rsqrtf(var + 1e-5f);
  float4 g4 = ((const float4*)gam)[t];
  float4 b4 = ((const float4*)bet)[t];
  float o0 = (v.x - mu) * rstd * g4.x + b4.x;
  float o1 = (v.y - mu) * rstd * g4.y + b4.y;
  float o2 = (v.z - mu) * rstd * g4.z + b4.z;
  float o3 = (v.w - mu) * rstd * g4.w + b4.w;
  if (out_ln) {
    bf16x4 q;
    q[0] = (bf16)o0; q[1] = (bf16)o1; q[2] = (bf16)o2; q[3] = (bf16)o3;
    *(bf16x4*)(out_ln + row * ND + t * 4) = q;
  }
  if (out_lnpos) {
    float4 p4 = ((const float4*)(pos + row * ND))[t];
    bf16x4 q;
    q[0] = (bf16)(o0 + p4.x); q[1] = (bf16)(o1 + p4.y);
    q[2] = (bf16)(o2 + p4.z); q[3] = (bf16)(o3 + p4.w);
    *(bf16x4*)(out_lnpos + row * ND + t * 4) = q;
  }
}

// ---- GEMM v4: C[M,N] = A[M,K] @ WT[N,K]^T + bias.
// BM=BN=128, BK=32, 256 thr (4 waves, 64x64/wave) -- m97-proven shape.
// 5-slot LDS ring (80 KB -> 2 blocks/CU), stage tile t+4 per phase,
// counted vmcnt(12) (T4), ONE raw s_barrier per phase, XOR chunk swizzle
// both sides (T2, rule #21), setprio around MFMA cluster (T5).
// MODE 0: bf16 out.  MODE 1: f32 out = res + v.  MODE 2: bf16 out = swish(v).
template <int MODE>
__global__ __launch_bounds__(256, 2) void gemm_bt(
    const bf16* __restrict__ A, const bf16* __restrict__ WT,
    const float* __restrict__ bias, const float* __restrict__ res,
    void* __restrict__ out, int M, int N, int K) {
  __shared__ bf16 SA[5][128 * 32];  // 40 KiB
  __shared__ bf16 SB[5][128 * 32];  // 40 KiB
  const int t = threadIdx.x;
  const int w = t >> 6, l = t & 63;
  const int wr = w >> 1, wc = w & 1;
  const int c = l & 15, g = l >> 4;
  const long row0 = (long)blockIdx.x * 128;
  const long col0 = (long)blockIdx.y * 128;
  const int NT = K >> 5;

  f32x4 acc[4][4];
#pragma unroll
  for (int m = 0; m < 4; ++m)
#pragma unroll
    for (int n = 0; n < 4; ++n) acc[m][n] = (f32x4){0.f, 0.f, 0.f, 0.f};

  // staging: wave w instr covers 16 rows x 4 chunks(16B); lane l -> row l>>2,
  // dest chunk u=l&3; source chunk = u ^ (row&3) (involution, rule #21).
  const int srow = l >> 2;
  const int schunk = 8 * ((l & 3) ^ (srow & 3));
  const bf16* Ag0 = A + (row0 + w * 16 + srow) * (long)K + schunk;
  const bf16* Ag1 = Ag0 + 64 * (long)K;
  const bf16* Bg0 = WT + (col0 + w * 16 + srow) * (long)K + schunk;
  const bf16* Bg1 = Bg0 + 64 * (long)K;
  bf16* const SAf = &SA[0][0];
  bf16* const SBf = &SB[0][0];

#define STAGE(SL, KK)                                  \
  do {                                                 \
    gload16(Ag0 + (KK), SAf + (SL) * 4096 + (w * 16) * 32);        \
    gload16(Ag1 + (KK), SAf + (SL) * 4096 + (64 + w * 16) * 32);   \
    gload16(Bg0 + (KK), SBf + (SL) * 4096 + (w * 16) * 32);        \
    gload16(Bg1 + (KK), SBf + (SL) * 4096 + (64 + w * 16) * 32);   \
  } while (0)

  // prologue: tiles 0..3 (16 loads/wave in flight)
  STAGE(0, 0);
  STAGE(1, 32);
  STAGE(2, 64);
  STAGE(3, 96);

  // read offsets: frag row = base + c, chunk g^(c&3)
  const int rsw = (g ^ (c & 3)) * 8;
  int aoff[4], boff[4];
#pragma unroll
  for (int m = 0; m < 4; ++m) aoff[m] = (wr * 64 + m * 16 + c) * 32 + rsw;
#pragma unroll
  for (int n = 0; n < 4; ++n) boff[n] = (wc * 64 + n * 16 + c) * 32 + rsw;

  int cb = 0, sb = 4;
  int kst = 128;
  for (int tt = 0; tt < NT; ++tt) {
    const int rem = NT - 1 - tt;
    if (rem >= 3) {
      asm volatile("s_waitcnt vmcnt(12)" ::: "memory");
    } else if (rem == 2) {
      asm volatile("s_waitcnt vmcnt(8)" ::: "memory");
    } else if (rem == 1) {
      asm volatile("s_waitcnt vmcnt(4)" ::: "memory");
    } else {
      asm volatile("s_waitcnt vmcnt(0)" ::: "memory");
    }
    __builtin_amdgcn_s_barrier();

    if (tt + 4 < NT) STAGE(sb, kst);

    const int ca = cb * 4096;
    bf16x8 af[4], bfr[4];
#pragma unroll
    for (int m = 0; m < 4; ++m) af[m] = *(const bf16x8*)(SAf + ca + aoff[m]);
#pragma unroll
    for (int n = 0; n < 4; ++n) bfr[n] = *(const bf16x8*)(SBf + ca + boff[n]);

    __builtin_amdgcn_s_setprio(1);
#pragma unroll
    for (int m = 0; m < 4; ++m)
#pragma unroll
      for (int n = 0; n < 4; ++n)
        acc[m][n] = __builtin_amdgcn_mfma_f32_16x16x32_bf16(af[m], bfr[n], acc[m][n], 0, 0, 0);
    __builtin_amdgcn_s_setprio(0);

    cb = (cb == 4) ? 0 : cb + 1;
    sb = (sb == 4) ? 0 : sb + 1;
    kst += 32;
  }
#undef STAGE

#pragma unroll
  for (int n = 0; n < 4; ++n) {
    const long col = col0 + wc * 64 + n * 16 + c;
    const float bv = bias[col];
#pragma unroll
    for (int m = 0; m < 4; ++m) {
      const long rowb = row0 + wr * 64 + m * 16 + g * 4;
#pragma unroll
      for (int r = 0; r < 4; ++r) {
        float v = acc[m][n][r] + bv;
        const long idx = (rowb + r) * N + col;
        if (MODE == 0) {
          ((bf16*)out)[idx] = (bf16)v;
        } else if (MODE == 1) {
          ((float*)out)[idx] = res[idx] + v;
        } else {
          float sw = v / (1.f + __expf(-v));
          ((bf16*)out)[idx] = (bf16)sw;
        }
      }
    }
  }
}

// ---- V transpose per head: V [B*S][D] -> VT [B*H][DK][S] ----
__global__ void vtrans(const bf16* __restrict__ V, bf16* __restrict__ VT) {
  __shared__ bf16 tile[32][33];
  int st = blockIdx.x * 32, dt = blockIdx.y * 32;
  int bh = blockIdx.z;
  int b = bh >> 4, h = bh & 15;
  int tx = threadIdx.x, ty = threadIdx.y;
#pragma unroll
  for (int i2 = 0; i2 < 4; ++i2) {
    int i = ty + i2 * 8;
    tile[i][tx] = V[((long)b * NS + st + i) * ND + h * NDK + dt + tx];
  }
  __syncthreads();
#pragma unroll
  for (int i2 = 0; i2 < 4; ++i2) {
    int i = ty + i2 * 8;
    VT[((long)bh * NDK + dt + i) * NS + st + tx] = tile[tx][i];
  }
}

// ---- flash attention v3 (unchanged) ----
__global__ __launch_bounds__(256) void attn_fwd(
    const bf16* __restrict__ Q, const bf16* __restrict__ Kt,
    const bf16* __restrict__ VT, bf16* __restrict__ O) {
  __shared__ bf16 Ks[2][64 * 64];
  __shared__ bf16 Vs[2][64 * 64];
  __shared__ bf16 Pl[4][2][16 * 68];
  int t = threadIdx.x;
  int w = t >> 6, l = t & 63;
  int c = l & 15, g = l >> 4;
  int bid = blockIdx.x;
  int qt = bid >> 7, bh = bid & 127;
  int b = bh >> 4, h = bh & 15;
  int q0 = qt * 128 + w * 32;
  int swz = (c & 7) << 4;

  bf16x8 qf[2][2];
  const bf16* Qbase = Q + (long)(b * NS) * ND + h * NDK;
#pragma unroll
  for (int sj = 0; sj < 2; ++sj) {
    const bf16* qr = Qbase + (long)(q0 + sj * 16 + c) * ND + g * 8;
    qf[sj][0] = *(const bf16x8*)qr;
    qf[sj][1] = *(const bf16x8*)(qr + 32);
  }

  const bf16* Kg = Kt + (long)(b * NS) * ND + h * NDK;
  const bf16* Vg = VT + (long)(b * NH + h) * NDK * NS;

  int sr = l >> 3;
  int sc8 = 8 * ((l & 7) ^ sr);

  f32x4 o[2][4];
#pragma unroll
  for (int sj = 0; sj < 2; ++sj)
#pragma unroll
    for (int ds = 0; ds < 4; ++ds) o[sj][ds] = (f32x4){0.f, 0.f, 0.f, 0.f};
  float mx[2] = {-1e30f, -1e30f};
  float lsum[2] = {0.f, 0.f};

#define STAGE(BUF, KV)                                                        \
  {                                                                           \
    _Pragma("unroll") for (int j = 0; j < 2; ++j) {                           \
      int row = w * 16 + j * 8 + sr;                                          \
      gload16(Kg + (long)((KV) + row) * ND + sc8,                             \
              &Ks[BUF][(w * 16 + j * 8) * 64]);                               \
      gload16(Vg + (long)row * NS + (KV) + sc8,                               \
              &Vs[BUF][(w * 16 + j * 8) * 64]);                               \
    }                                                                         \
  }

  STAGE(0, 0);
  asm volatile("s_waitcnt vmcnt(0)" ::: "memory");
  __syncthreads();

  int buf = 0;
  for (int it = 0; it < NS / 64; ++it) {
    if (it + 1 < NS / 64) STAGE(buf ^ 1, (it + 1) * 64);

    f32x4 sv[2][4];
#pragma unroll
    for (int sj = 0; sj < 2; ++sj)
#pragma unroll
      for (int kt = 0; kt < 4; ++kt) sv[sj][kt] = (f32x4){0.f, 0.f, 0.f, 0.f};
    __builtin_amdgcn_s_setprio(1);
#pragma unroll
    for (int kt = 0; kt < 4; ++kt) {
      const char* kr = (const char*)&Ks[buf][(kt * 16 + c) * 64];
      bf16x8 ka0 = *(const bf16x8*)(kr + ((g * 16) ^ swz));
      bf16x8 ka1 = *(const bf16x8*)(kr + ((64 + g * 16) ^ swz));
#pragma unroll
      for (int sj = 0; sj < 2; ++sj) {
        sv[sj][kt] = __builtin_amdgcn_mfma_f32_16x16x32_bf16(ka0, qf[sj][0], sv[sj][kt], 0, 0, 0);
        sv[sj][kt] = __builtin_amdgcn_mfma_f32_16x16x32_bf16(ka1, qf[sj][1], sv[sj][kt], 0, 0, 0);
      }
    }
    __builtin_amdgcn_s_setprio(0);

    float pm[2];
#pragma unroll
    for (int sj = 0; sj < 2; ++sj) {
      float m = -1e30f;
#pragma unroll
      for (int kt = 0; kt < 4; ++kt)
#pragma unroll
        for (int r = 0; r < 4; ++r) {
          sv[sj][kt][r] *= 0.125f;
          m = fmaxf(m, sv[sj][kt][r]);
        }
      m = fmaxf(m, __shfl_xor(m, 16));
      m = fmaxf(m, __shfl_xor(m, 32));
      pm[sj] = m;
    }
    int cond = (pm[0] <= mx[0] + 8.f) && (pm[1] <= mx[1] + 8.f);
    if (!__all(cond)) {
#pragma unroll
      for (int sj = 0; sj < 2; ++sj) {
        float mn = fmaxf(mx[sj], pm[sj]);
        float sc = __expf(mx[sj] - mn);
        mx[sj] = mn;
        lsum[sj] *= sc;
#pragma unroll
        for (int ds = 0; ds < 4; ++ds)
#pragma unroll
          for (int r = 0; r < 4; ++r) o[sj][ds][r] *= sc;
      }
    }
#pragma unroll
    for (int sj = 0; sj < 2; ++sj) {
      float rs = 0.f;
#pragma unroll
      for (int kt = 0; kt < 4; ++kt) {
        bf16x4 pw;
#pragma unroll
        for (int r = 0; r < 4; ++r) {
          float e = __expf(sv[sj][kt][r] - mx[sj]);
          rs += e;
          pw[r] = (bf16)e;
        }
        *(bf16x4*)&Pl[w][sj][c * 68 + kt * 16 + 4 * g] = pw;
      }
      rs += __shfl_xor(rs, 16);
      rs += __shfl_xor(rs, 32);
      lsum[sj] += rs;
    }
    asm volatile("s_waitcnt lgkmcnt(0)" ::: "memory");
    __builtin_amdgcn_sched_barrier(0);

    __builtin_amdgcn_s_setprio(1);
#pragma unroll
    for (int ks = 0; ks < 2; ++ks) {
      bf16x8 pb0 = *(const bf16x8*)&Pl[w][0][c * 68 + ks * 32 + g * 8];
      bf16x8 pb1 = *(const bf16x8*)&Pl[w][1][c * 68 + ks * 32 + g * 8];
#pragma unroll
      for (int ds = 0; ds < 4; ++ds) {
        const char* vr = (const char*)&Vs[buf][(ds * 16 + c) * 64];
        bf16x8 va = *(const bf16x8*)(vr + ((ks * 64 + g * 16) ^ swz));
        o[0][ds] = __builtin_amdgcn_mfma_f32_16x16x32_bf16(va, pb0, o[0][ds], 0, 0, 0);
        o[1][ds] = __builtin_amdgcn_mfma_f32_16x16x32_bf16(va, pb1, o[1][ds], 0, 0, 0);
      }
    }
    __builtin_amdgcn_s_setprio(0);
    __syncthreads();
    buf ^= 1;
  }

#pragma unroll
  for (int sj = 0; sj < 2; ++sj) {
    float inv = 1.f / lsum[sj];
    bf16* Orow = O + (long)(b * NS + q0 + sj * 16 + c) * ND + h * NDK;
#pragma unroll
    for (int ds = 0; ds < 4; ++ds) {
      bf16x4 ov;
#pragma unroll
      for (int r = 0; r < 4; ++r) ov[r] = (bf16)(o[sj][ds][r] * inv);
      *(bf16x4*)(Orow + ds * 16 + 4 * g) = ov;
    }
  }
#undef STAGE
}

extern "C" void kernel_launch(void* const* d_in, const int* in_sizes, int n_in,
                              void* d_out, int out_size, void* d_ws, size_t ws_size,
                              hipStream_t stream) {
  (void)in_sizes; (void)n_in; (void)out_size; (void)ws_size;
  const float* x = (const float*)d_in[0];
  const float* y = (const float*)d_in[1];
  const float* x_pos = (const float*)d_in[2];
  const float* y_pos = (const float*)d_in[3];

  char* ws = (char*)d_ws;
  const size_t MB = 1ull << 20;
  bf16* Wt[8];
  for (int i = 0; i < 8; ++i) Wt[i] = (bf16*)(ws + (size_t)i * 2 * MB);
  bf16* W1T = (bf16*)(ws + 16 * MB);
  bf16* W2T = (bf16*)(ws + 24 * MB);
  float* xres = (float*)(ws + 32 * MB);
  bf16* x2 = (bf16*)(ws + 64 * MB);
  bf16* qk = (bf16*)(ws + 80 * MB);
  bf16* y2 = (bf16*)(ws + 96 * MB);
  bf16* yk = (bf16*)(ws + 112 * MB);
  bf16* Qb = (bf16*)(ws + 128 * MB);
  bf16* Kb = (bf16*)(ws + 144 * MB);
  bf16* Vb = (bf16*)(ws + 160 * MB);
  bf16* VTb = (bf16*)(ws + 176 * MB);
  bf16* Ob = (bf16*)(ws + 192 * MB);
  bf16* hb = (bf16*)(ws + 128 * MB);  // aliases Qb..VTb (free during FFN)

  dim3 tb(32, 8);
  for (int i = 0; i < 8; ++i)
    wconv_t<<<dim3(32, 32), tb, 0, stream>>>((const float*)d_in[4 + 2 * i], Wt[i], 1024, 1024);
  wconv_t<<<dim3(128, 32), tb, 0, stream>>>((const float*)d_in[20], W1T, 1024, 4096);
  wconv_t<<<dim3(32, 128), tb, 0, stream>>>((const float*)d_in[22], W2T, 4096, 1024);

  const float* ln1g = (const float*)d_in[24]; const float* ln1b = (const float*)d_in[25];
  const float* ln2g = (const float*)d_in[26]; const float* ln2b = (const float*)d_in[27];
  const float* ln3g = (const float*)d_in[28]; const float* ln3b = (const float*)d_in[29];
  const float* ln4g = (const float*)d_in[30]; const float* ln4b = (const float*)d_in[31];

  dim3 gD(64, 8);    // M-tiles(128) x N-tiles(128)
  dim3 gF1(64, 32);
  dim3 gVT(32, 2, 128);

  // ---- self-attention ----
  ln_fused<<<8192, 256, 0, stream>>>(x, ln1g, ln1b, x_pos, x2, qk);
  gemm_bt<0><<<gD, 256, 0, stream>>>(qk, Wt[0], (const float*)d_in[5], nullptr, Qb, 8192, 1024, 1024);
  gemm_bt<0><<<gD, 256, 0, stream>>>(qk, Wt[1], (const float*)d_in[7], nullptr, Kb, 8192, 1024, 1024);
  gemm_bt<0><<<gD, 256, 0, stream>>>(x2, Wt[2], (const float*)d_in[9], nullptr, Vb, 8192, 1024, 1024);
  vtrans<<<gVT, tb, 0, stream>>>(Vb, VTb);
  attn_fwd<<<1024, 256, 0, stream>>>(Qb, Kb, VTb, Ob);
  gemm_bt<1><<<gD, 256, 0, stream>>>(Ob, Wt[3], (const float*)d_in[11], x, xres, 8192, 1024, 1024);

  // ---- cross-attention ----
  ln_fused<<<8192, 256, 0, stream>>>(xres, ln2g, ln2b, x_pos, nullptr, qk);
  ln_fused<<<8192, 256, 0, stream>>>(y, ln3g, ln3b, y_pos, y2, yk);
  gemm_bt<0><<<gD, 256, 0, stream>>>(qk, Wt[4], (const float*)d_in[13], nullptr, Qb, 8192, 1024, 1024);
  gemm_bt<0><<<gD, 256, 0, stream>>>(yk, Wt[5], (const float*)d_in[15], nullptr, Kb, 8192, 1024, 1024);
  gemm_bt<0><<<gD, 256, 0, stream>>>(y2, Wt[6], (const float*)d_in[17], nullptr, Vb, 8192, 1024, 1024);
  vtrans<<<gVT, tb, 0, stream>>>(Vb, VTb);
  attn_fwd<<<1024, 256, 0, stream>>>(Qb, Kb, VTb, Ob);
  gemm_bt<1><<<gD, 256, 0, stream>>>(Ob, Wt[7], (const float*)d_in[19], xres, xres, 8192, 1024, 1024);

  // ---- FFN ----
  ln_fused<<<8192, 256, 0, stream>>>(xres, ln4g, ln4b, nullptr, x2, nullptr);
  gemm_bt<2><<<gF1, 256, 0, stream>>>(x2, W1T, (const float*)d_in[21], nullptr, hb, 8192, 4096, 1024);
  gemm_bt<1><<<gD, 256, 0, stream>>>(hb, W2T, (const float*)d_in[23], xres, (float*)d_out, 8192, 1024, 4096);
}

// Round 7
// 717.239 us; speedup vs baseline: 1.0661x; 1.0661x over previous
//
#include <hip/hip_runtime.h>
#include <hip/hip_bf16.h>

#define NB 8
#define NS 1024
#define ND 1024
#define NH 16
#define NDK 64
#define NDFF 4096

typedef __bf16 bf16;
typedef __attribute__((ext_vector_type(8))) __bf16 bf16x8;
typedef __attribute__((ext_vector_type(4))) __bf16 bf16x4;
typedef __attribute__((ext_vector_type(4))) float f32x4;

__device__ __forceinline__ void gload16(const bf16* g, bf16* l) {
  __builtin_amdgcn_global_load_lds(
      (const __attribute__((address_space(1))) void*)g,
      (__attribute__((address_space(3))) void*)l, 16, 0, 0);
}

// ---- weight convert + transpose: W f32 [K][N] -> WT bf16 [N][K] ----
__global__ void wconv_t(const float* __restrict__ W, bf16* __restrict__ WT,
                        int K, int N) {
  __shared__ float tile[32][33];
  int n0 = blockIdx.x * 32, k0 = blockIdx.y * 32;
  int tx = threadIdx.x, ty = threadIdx.y;
#pragma unroll
  for (int i2 = 0; i2 < 4; ++i2) {
    int i = ty + i2 * 8;
    tile[i][tx] = W[(long)(k0 + i) * N + n0 + tx];
  }
  __syncthreads();
#pragma unroll
  for (int i2 = 0; i2 < 4; ++i2) {
    int i = ty + i2 * 8;
    WT[(long)(n0 + i) * K + k0 + tx] = (bf16)tile[tx][i];
  }
}

// ---- fused layernorm: out_ln = bf16(LN(x)), out_lnpos = bf16(LN(x)+pos) ----
__global__ void ln_fused(const float* __restrict__ in, const float* __restrict__ gam,
                         const float* __restrict__ bet, const float* __restrict__ pos,
                         bf16* __restrict__ out_ln, bf16* __restrict__ out_lnpos) {
  long row = blockIdx.x;
  int t = threadIdx.x;  // 256
  float4 v = ((const float4*)(in + row * ND))[t];
  float s = v.x + v.y + v.z + v.w;
  float s2 = v.x * v.x + v.y * v.y + v.z * v.z + v.w * v.w;
#pragma unroll
  for (int m = 32; m >= 1; m >>= 1) {
    s += __shfl_xor(s, m);
    s2 += __shfl_xor(s2, m);
  }
  __shared__ float red[8];
  if ((t & 63) == 0) {
    red[t >> 6] = s;
    red[4 + (t >> 6)] = s2;
  }
  __syncthreads();
  float ts = red[0] + red[1] + red[2] + red[3];
  float ts2 = red[4] + red[5] + red[6] + red[7];
  float mu = ts * (1.0f / ND);
  float var = ts2 * (1.0f / ND) - mu * mu;
  float rstd = rsqrtf(var + 1e-5f);
  float4 g4 = ((const float4*)gam)[t];
  float4 b4 = ((const float4*)bet)[t];
  float o0 = (v.x - mu) * rstd * g4.x + b4.x;
  float o1 = (v.y - mu) * rstd * g4.y + b4.y;
  float o2 = (v.z - mu) * rstd * g4.z + b4.z;
  float o3 = (v.w - mu) * rstd * g4.w + b4.w;
  if (out_ln) {
    bf16x4 q;
    q[0] = (bf16)o0; q[1] = (bf16)o1; q[2] = (bf16)o2; q[3] = (bf16)o3;
    *(bf16x4*)(out_ln + row * ND + t * 4) = q;
  }
  if (out_lnpos) {
    float4 p4 = ((const float4*)(pos + row * ND))[t];
    bf16x4 q;
    q[0] = (bf16)(o0 + p4.x); q[1] = (bf16)(o1 + p4.y);
    q[2] = (bf16)(o2 + p4.z); q[3] = (bf16)(o3 + p4.w);
    *(bf16x4*)(out_lnpos + row * ND + t * 4) = q;
  }
}

// ---- GEMM v5: m201-style two-barrier phase schedule.
// BM=256 BN=128 BK=32, 512 thr (8 waves 2M x 4N, wave tile 128x32).
// Per phase (= per K-tile): {10 ds_read | stage tile t+2 (3 gload) |
//   s_barrier | lgkmcnt(0)+sched_barrier | setprio(1) 16 MFMA setprio(0) |
//   counted vmcnt(3) | s_barrier}.  4-slot LDS ring (96 KB, 1 block/CU).
// Swizzle (round-5 verified 0-conflict): store src slot u^((row>>1)&3),
// read slot g^((c>>1)&3)  -> 2-way max (free).
// MODE 0: bf16 out.  MODE 1: f32 out = res + v.  MODE 2: bf16 out = swish(v).
template <int MODE>
__global__ __launch_bounds__(512, 1) void gemm_bt(
    const bf16* __restrict__ A, const bf16* __restrict__ WT,
    const float* __restrict__ bias, const float* __restrict__ res,
    void* __restrict__ out, int M, int N, int K) {
  __shared__ bf16 SA[4][256 * 32];  // 64 KiB
  __shared__ bf16 SB[4][128 * 32];  // 32 KiB
  const int t = threadIdx.x;
  const int w = t >> 6, l = t & 63;
  const int wr = w >> 2;   // M-half (0..1): rows wr*128
  const int wc = w & 3;    // N-quarter (0..3): cols wc*32
  const int c = l & 15, g = l >> 4;
  const long row0 = (long)blockIdx.x * 256;
  const long col0 = (long)blockIdx.y * 128;
  const int NT = K >> 5;

  f32x4 acc[8][2];
#pragma unroll
  for (int m = 0; m < 8; ++m)
#pragma unroll
    for (int n = 0; n < 2; ++n) acc[m][n] = (f32x4){0.f, 0.f, 0.f, 0.f};

  // staging: per wave-instr 16 rows x 64B; lane l -> row l>>2, dest slot l&3,
  // source slot (l&3)^((l>>3)&3)  [= (l&3)^((row>>1)&3), involution]
  const int srow = l >> 2;
  const int sslot = 8 * ((l & 3) ^ ((l >> 3) & 3));
  const bf16* AgA = A + (row0 + w * 16 + srow) * (long)K + sslot;
  const bf16* AgB = A + (row0 + 128 + w * 16 + srow) * (long)K + sslot;
  const bf16* BgA = WT + (col0 + w * 16 + srow) * (long)K + sslot;

#define STAGE(SL, KK)                                      \
  do {                                                     \
    gload16(AgA + (KK), &SA[SL][(w * 16) * 32]);           \
    gload16(AgB + (KK), &SA[SL][(128 + w * 16) * 32]);     \
    gload16(BgA + (KK), &SB[SL][(w * 16) * 32]);           \
  } while (0)

  // read offsets (element units), loop-invariant, fully static
  const int rsw = (g ^ ((c >> 1) & 3)) * 8;
  int aoff[8], boff[2];
#pragma unroll
  for (int m = 0; m < 8; ++m) aoff[m] = (wr * 128 + m * 16 + c) * 32 + rsw;
#pragma unroll
  for (int n = 0; n < 2; ++n) boff[n] = (wc * 32 + n * 16 + c) * 32 + rsw;

  // prologue: tiles 0,1 staged (6 loads in flight); wait tile 0 (leave 3)
  STAGE(0, 0);
  STAGE(1, 32);
  asm volatile("s_waitcnt vmcnt(3)" ::: "memory");
  __builtin_amdgcn_s_barrier();

  for (int tt = 0; tt < NT; ++tt) {
    const int cb = tt & 3;
    bf16x8 af[8], bfr[2];
#pragma unroll
    for (int m = 0; m < 8; ++m) af[m] = *(const bf16x8*)&SA[cb][aoff[m]];
#pragma unroll
    for (int n = 0; n < 2; ++n) bfr[n] = *(const bf16x8*)&SB[cb][boff[n]];

    if (tt + 2 < NT) STAGE((tt + 2) & 3, (tt + 2) << 5);

    __builtin_amdgcn_s_barrier();
    asm volatile("s_waitcnt lgkmcnt(0)" ::: "memory");
    __builtin_amdgcn_sched_barrier(0);
    __builtin_amdgcn_s_setprio(1);
#pragma unroll
    for (int m = 0; m < 8; ++m)
#pragma unroll
      for (int n = 0; n < 2; ++n)
        acc[m][n] = __builtin_amdgcn_mfma_f32_16x16x32_bf16(af[m], bfr[n], acc[m][n], 0, 0, 0);
    __builtin_amdgcn_s_setprio(0);

    if (tt + 2 < NT) {
      asm volatile("s_waitcnt vmcnt(3)" ::: "memory");
    } else {
      asm volatile("s_waitcnt vmcnt(0)" ::: "memory");
    }
    __builtin_amdgcn_s_barrier();
  }
#undef STAGE

#pragma unroll
  for (int n = 0; n < 2; ++n) {
    const long col = col0 + wc * 32 + n * 16 + c;
    const float bv = bias[col];
#pragma unroll
    for (int m = 0; m < 8; ++m) {
      const long rowb = row0 + wr * 128 + m * 16 + g * 4;
#pragma unroll
      for (int r = 0; r < 4; ++r) {
        float v = acc[m][n][r] + bv;
        const long idx = (rowb + r) * N + col;
        if (MODE == 0) {
          ((bf16*)out)[idx] = (bf16)v;
        } else if (MODE == 1) {
          ((float*)out)[idx] = res[idx] + v;
        } else {
          float sw = v / (1.f + __expf(-v));
          ((bf16*)out)[idx] = (bf16)sw;
        }
      }
    }
  }
}

// ---- V transpose per head: V [B*S][D] -> VT [B*H][DK][S] ----
__global__ void vtrans(const bf16* __restrict__ V, bf16* __restrict__ VT) {
  __shared__ bf16 tile[32][33];
  int st = blockIdx.x * 32, dt = blockIdx.y * 32;
  int bh = blockIdx.z;
  int b = bh >> 4, h = bh & 15;
  int tx = threadIdx.x, ty = threadIdx.y;
#pragma unroll
  for (int i2 = 0; i2 < 4; ++i2) {
    int i = ty + i2 * 8;
    tile[i][tx] = V[((long)b * NS + st + i) * ND + h * NDK + dt + tx];
  }
  __syncthreads();
#pragma unroll
  for (int i2 = 0; i2 < 4; ++i2) {
    int i = ty + i2 * 8;
    VT[((long)bh * NDK + dt + i) * NS + st + tx] = tile[tx][i];
  }
}

// ---- flash attention v3 (unchanged) ----
__global__ __launch_bounds__(256) void attn_fwd(
    const bf16* __restrict__ Q, const bf16* __restrict__ Kt,
    const bf16* __restrict__ VT, bf16* __restrict__ O) {
  __shared__ bf16 Ks[2][64 * 64];
  __shared__ bf16 Vs[2][64 * 64];
  __shared__ bf16 Pl[4][2][16 * 68];
  int t = threadIdx.x;
  int w = t >> 6, l = t & 63;
  int c = l & 15, g = l >> 4;
  int bid = blockIdx.x;
  int qt = bid >> 7, bh = bid & 127;
  int b = bh >> 4, h = bh & 15;
  int q0 = qt * 128 + w * 32;
  int swz = (c & 7) << 4;

  bf16x8 qf[2][2];
  const bf16* Qbase = Q + (long)(b * NS) * ND + h * NDK;
#pragma unroll
  for (int sj = 0; sj < 2; ++sj) {
    const bf16* qr = Qbase + (long)(q0 + sj * 16 + c) * ND + g * 8;
    qf[sj][0] = *(const bf16x8*)qr;
    qf[sj][1] = *(const bf16x8*)(qr + 32);
  }

  const bf16* Kg = Kt + (long)(b * NS) * ND + h * NDK;
  const bf16* Vg = VT + (long)(b * NH + h) * NDK * NS;

  int sr = l >> 3;
  int sc8 = 8 * ((l & 7) ^ sr);

  f32x4 o[2][4];
#pragma unroll
  for (int sj = 0; sj < 2; ++sj)
#pragma unroll
    for (int ds = 0; ds < 4; ++ds) o[sj][ds] = (f32x4){0.f, 0.f, 0.f, 0.f};
  float mx[2] = {-1e30f, -1e30f};
  float lsum[2] = {0.f, 0.f};

#define STAGE(BUF, KV)                                                        \
  {                                                                           \
    _Pragma("unroll") for (int j = 0; j < 2; ++j) {                           \
      int row = w * 16 + j * 8 + sr;                                          \
      gload16(Kg + (long)((KV) + row) * ND + sc8,                             \
              &Ks[BUF][(w * 16 + j * 8) * 64]);                               \
      gload16(Vg + (long)row * NS + (KV) + sc8,                               \
              &Vs[BUF][(w * 16 + j * 8) * 64]);                               \
    }                                                                         \
  }

  STAGE(0, 0);
  asm volatile("s_waitcnt vmcnt(0)" ::: "memory");
  __syncthreads();

  int buf = 0;
  for (int it = 0; it < NS / 64; ++it) {
    if (it + 1 < NS / 64) STAGE(buf ^ 1, (it + 1) * 64);

    f32x4 sv[2][4];
#pragma unroll
    for (int sj = 0; sj < 2; ++sj)
#pragma unroll
      for (int kt = 0; kt < 4; ++kt) sv[sj][kt] = (f32x4){0.f, 0.f, 0.f, 0.f};
    __builtin_amdgcn_s_setprio(1);
#pragma unroll
    for (int kt = 0; kt < 4; ++kt) {
      const char* kr = (const char*)&Ks[buf][(kt * 16 + c) * 64];
      bf16x8 ka0 = *(const bf16x8*)(kr + ((g * 16) ^ swz));
      bf16x8 ka1 = *(const bf16x8*)(kr + ((64 + g * 16) ^ swz));
#pragma unroll
      for (int sj = 0; sj < 2; ++sj) {
        sv[sj][kt] = __builtin_amdgcn_mfma_f32_16x16x32_bf16(ka0, qf[sj][0], sv[sj][kt], 0, 0, 0);
        sv[sj][kt] = __builtin_amdgcn_mfma_f32_16x16x32_bf16(ka1, qf[sj][1], sv[sj][kt], 0, 0, 0);
      }
    }
    __builtin_amdgcn_s_setprio(0);

    float pm[2];
#pragma unroll
    for (int sj = 0; sj < 2; ++sj) {
      float m = -1e30f;
#pragma unroll
      for (int kt = 0; kt < 4; ++kt)
#pragma unroll
        for (int r = 0; r < 4; ++r) {
          sv[sj][kt][r] *= 0.125f;
          m = fmaxf(m, sv[sj][kt][r]);
        }
      m = fmaxf(m, __shfl_xor(m, 16));
      m = fmaxf(m, __shfl_xor(m, 32));
      pm[sj] = m;
    }
    int cond = (pm[0] <= mx[0] + 8.f) && (pm[1] <= mx[1] + 8.f);
    if (!__all(cond)) {
#pragma unroll
      for (int sj = 0; sj < 2; ++sj) {
        float mn = fmaxf(mx[sj], pm[sj]);
        float sc = __expf(mx[sj] - mn);
        mx[sj] = mn;
        lsum[sj] *= sc;
#pragma unroll
        for (int ds = 0; ds < 4; ++ds)
#pragma unroll
          for (int r = 0; r < 4; ++r) o[sj][ds][r] *= sc;
      }
    }
#pragma unroll
    for (int sj = 0; sj < 2; ++sj) {
      float rs = 0.f;
#pragma unroll
      for (int kt = 0; kt < 4; ++kt) {
        bf16x4 pw;
#pragma unroll
        for (int r = 0; r < 4; ++r) {
          float e = __expf(sv[sj][kt][r] - mx[sj]);
          rs += e;
          pw[r] = (bf16)e;
        }
        *(bf16x4*)&Pl[w][sj][c * 68 + kt * 16 + 4 * g] = pw;
      }
      rs += __shfl_xor(rs, 16);
      rs += __shfl_xor(rs, 32);
      lsum[sj] += rs;
    }
    asm volatile("s_waitcnt lgkmcnt(0)" ::: "memory");
    __builtin_amdgcn_sched_barrier(0);

    __builtin_amdgcn_s_setprio(1);
#pragma unroll
    for (int ks = 0; ks < 2; ++ks) {
      bf16x8 pb0 = *(const bf16x8*)&Pl[w][0][c * 68 + ks * 32 + g * 8];
      bf16x8 pb1 = *(const bf16x8*)&Pl[w][1][c * 68 + ks * 32 + g * 8];
#pragma unroll
      for (int ds = 0; ds < 4; ++ds) {
        const char* vr = (const char*)&Vs[buf][(ds * 16 + c) * 64];
        bf16x8 va = *(const bf16x8*)(vr + ((ks * 64 + g * 16) ^ swz));
        o[0][ds] = __builtin_amdgcn_mfma_f32_16x16x32_bf16(va, pb0, o[0][ds], 0, 0, 0);
        o[1][ds] = __builtin_amdgcn_mfma_f32_16x16x32_bf16(va, pb1, o[1][ds], 0, 0, 0);
      }
    }
    __builtin_amdgcn_s_setprio(0);
    __syncthreads();
    buf ^= 1;
  }

#pragma unroll
  for (int sj = 0; sj < 2; ++sj) {
    float inv = 1.f / lsum[sj];
    bf16* Orow = O + (long)(b * NS + q0 + sj * 16 + c) * ND + h * NDK;
#pragma unroll
    for (int ds = 0; ds < 4; ++ds) {
      bf16x4 ov;
#pragma unroll
      for (int r = 0; r < 4; ++r) ov[r] = (bf16)(o[sj][ds][r] * inv);
      *(bf16x4*)(Orow + ds * 16 + 4 * g) = ov;
    }
  }
#undef STAGE
}

extern "C" void kernel_launch(void* const* d_in, const int* in_sizes, int n_in,
                              void* d_out, int out_size, void* d_ws, size_t ws_size,
                              hipStream_t stream) {
  (void)in_sizes; (void)n_in; (void)out_size; (void)ws_size;
  const float* x = (const float*)d_in[0];
  const float* y = (const float*)d_in[1];
  const float* x_pos = (const float*)d_in[2];
  const float* y_pos = (const float*)d_in[3];

  char* ws = (char*)d_ws;
  const size_t MB = 1ull << 20;
  bf16* Wt[8];
  for (int i = 0; i < 8; ++i) Wt[i] = (bf16*)(ws + (size_t)i * 2 * MB);
  bf16* W1T = (bf16*)(ws + 16 * MB);
  bf16* W2T = (bf16*)(ws + 24 * MB);
  float* xres = (float*)(ws + 32 * MB);
  bf16* x2 = (bf16*)(ws + 64 * MB);
  bf16* qk = (bf16*)(ws + 80 * MB);
  bf16* y2 = (bf16*)(ws + 96 * MB);
  bf16* yk = (bf16*)(ws + 112 * MB);
  bf16* Qb = (bf16*)(ws + 128 * MB);
  bf16* Kb = (bf16*)(ws + 144 * MB);
  bf16* Vb = (bf16*)(ws + 160 * MB);
  bf16* VTb = (bf16*)(ws + 176 * MB);
  bf16* Ob = (bf16*)(ws + 192 * MB);
  bf16* hb = (bf16*)(ws + 128 * MB);  // aliases Qb..VTb (free during FFN)

  dim3 tb(32, 8);
  for (int i = 0; i < 8; ++i)
    wconv_t<<<dim3(32, 32), tb, 0, stream>>>((const float*)d_in[4 + 2 * i], Wt[i], 1024, 1024);
  wconv_t<<<dim3(128, 32), tb, 0, stream>>>((const float*)d_in[20], W1T, 1024, 4096);
  wconv_t<<<dim3(32, 128), tb, 0, stream>>>((const float*)d_in[22], W2T, 4096, 1024);

  const float* ln1g = (const float*)d_in[24]; const float* ln1b = (const float*)d_in[25];
  const float* ln2g = (const float*)d_in[26]; const float* ln2b = (const float*)d_in[27];
  const float* ln3g = (const float*)d_in[28]; const float* ln3b = (const float*)d_in[29];
  const float* ln4g = (const float*)d_in[30]; const float* ln4b = (const float*)d_in[31];

  dim3 gD(32, 8);     // M-tiles(256) x N-tiles(128)
  dim3 gF1(32, 32);
  dim3 gVT(32, 2, 128);

  // ---- self-attention ----
  ln_fused<<<8192, 256, 0, stream>>>(x, ln1g, ln1b, x_pos, x2, qk);
  gemm_bt<0><<<gD, 512, 0, stream>>>(qk, Wt[0], (const float*)d_in[5], nullptr, Qb, 8192, 1024, 1024);
  gemm_bt<0><<<gD, 512, 0, stream>>>(qk, Wt[1], (const float*)d_in[7], nullptr, Kb, 8192, 1024, 1024);
  gemm_bt<0><<<gD, 512, 0, stream>>>(x2, Wt[2], (const float*)d_in[9], nullptr, Vb, 8192, 1024, 1024);
  vtrans<<<gVT, tb, 0, stream>>>(Vb, VTb);
  attn_fwd<<<1024, 256, 0, stream>>>(Qb, Kb, VTb, Ob);
  gemm_bt<1><<<gD, 512, 0, stream>>>(Ob, Wt[3], (const float*)d_in[11], x, xres, 8192, 1024, 1024);

  // ---- cross-attention ----
  ln_fused<<<8192, 256, 0, stream>>>(xres, ln2g, ln2b, x_pos, nullptr, qk);
  ln_fused<<<8192, 256, 0, stream>>>(y, ln3g, ln3b, y_pos, y2, yk);
  gemm_bt<0><<<gD, 512, 0, stream>>>(qk, Wt[4], (const float*)d_in[13], nullptr, Qb, 8192, 1024, 1024);
  gemm_bt<0><<<gD, 512, 0, stream>>>(yk, Wt[5], (const float*)d_in[15], nullptr, Kb, 8192, 1024, 1024);
  gemm_bt<0><<<gD, 512, 0, stream>>>(y2, Wt[6], (const float*)d_in[17], nullptr, Vb, 8192, 1024, 1024);
  vtrans<<<gVT, tb, 0, stream>>>(Vb, VTb);
  attn_fwd<<<1024, 256, 0, stream>>>(Qb, Kb, VTb, Ob);
  gemm_bt<1><<<gD, 512, 0, stream>>>(Ob, Wt[7], (const float*)d_in[19], xres, xres, 8192, 1024, 1024);

  // ---- FFN ----
  ln_fused<<<8192, 256, 0, stream>>>(xres, ln4g, ln4b, nullptr, x2, nullptr);
  gemm_bt<2><<<gF1, 512, 0, stream>>>(x2, W1T, (const float*)d_in[21], nullptr, hb, 8192, 4096, 1024);
  gemm_bt<1><<<gD, 512, 0, stream>>>(hb, W2T, (const float*)d_in[23], xres, (float*)d_out, 8192, 1024, 4096);
}

// Round 8
// 671.650 us; speedup vs baseline: 1.1384x; 1.0679x over previous
//
#include <hip/hip_runtime.h>
#include <hip/hip_bf16.h>

#define NB 8
#define NS 1024
#define ND 1024
#define NH 16
#define NDK 64
#define NDFF 4096

typedef __bf16 bf16;
typedef __attribute__((ext_vector_type(8))) __bf16 bf16x8;
typedef __attribute__((ext_vector_type(4))) __bf16 bf16x4;
typedef __attribute__((ext_vector_type(4))) float f32x4;

__device__ __forceinline__ void gload16(const bf16* g, bf16* l) {
  __builtin_amdgcn_global_load_lds(
      (const __attribute__((address_space(1))) void*)g,
      (__attribute__((address_space(3))) void*)l, 16, 0, 0);
}

// ---- weight convert + transpose: W f32 [K][N] -> WT bf16 [N][K] ----
__global__ void wconv_t(const float* __restrict__ W, bf16* __restrict__ WT,
                        int K, int N) {
  __shared__ float tile[32][33];
  int n0 = blockIdx.x * 32, k0 = blockIdx.y * 32;
  int tx = threadIdx.x, ty = threadIdx.y;
#pragma unroll
  for (int i2 = 0; i2 < 4; ++i2) {
    int i = ty + i2 * 8;
    tile[i][tx] = W[(long)(k0 + i) * N + n0 + tx];
  }
  __syncthreads();
#pragma unroll
  for (int i2 = 0; i2 < 4; ++i2) {
    int i = ty + i2 * 8;
    WT[(long)(n0 + i) * K + k0 + tx] = (bf16)tile[tx][i];
  }
}

// ---- fused layernorm: out_ln = bf16(LN(x)), out_lnpos = bf16(LN(x)+pos) ----
__global__ void ln_fused(const float* __restrict__ in, const float* __restrict__ gam,
                         const float* __restrict__ bet, const float* __restrict__ pos,
                         bf16* __restrict__ out_ln, bf16* __restrict__ out_lnpos) {
  long row = blockIdx.x;
  int t = threadIdx.x;  // 256
  float4 v = ((const float4*)(in + row * ND))[t];
  float s = v.x + v.y + v.z + v.w;
  float s2 = v.x * v.x + v.y * v.y + v.z * v.z + v.w * v.w;
#pragma unroll
  for (int m = 32; m >= 1; m >>= 1) {
    s += __shfl_xor(s, m);
    s2 += __shfl_xor(s2, m);
  }
  __shared__ float red[8];
  if ((t & 63) == 0) {
    red[t >> 6] = s;
    red[4 + (t >> 6)] = s2;
  }
  __syncthreads();
  float ts = red[0] + red[1] + red[2] + red[3];
  float ts2 = red[4] + red[5] + red[6] + red[7];
  float mu = ts * (1.0f / ND);
  float var = ts2 * (1.0f / ND) - mu * mu;
  float rstd = rsqrtf(var + 1e-5f);
  float4 g4 = ((const float4*)gam)[t];
  float4 b4 = ((const float4*)bet)[t];
  float o0 = (v.x - mu) * rstd * g4.x + b4.x;
  float o1 = (v.y - mu) * rstd * g4.y + b4.y;
  float o2 = (v.z - mu) * rstd * g4.z + b4.z;
  float o3 = (v.w - mu) * rstd * g4.w + b4.w;
  if (out_ln) {
    bf16x4 q;
    q[0] = (bf16)o0; q[1] = (bf16)o1; q[2] = (bf16)o2; q[3] = (bf16)o3;
    *(bf16x4*)(out_ln + row * ND + t * 4) = q;
  }
  if (out_lnpos) {
    float4 p4 = ((const float4*)(pos + row * ND))[t];
    bf16x4 q;
    q[0] = (bf16)(o0 + p4.x); q[1] = (bf16)(o1 + p4.y);
    q[2] = (bf16)(o2 + p4.z); q[3] = (bf16)(o3 + p4.w);
    *(bf16x4*)(out_lnpos + row * ND + t * 4) = q;
  }
}

// ---- GEMM v6: concurrency-first. BM=BN=128, BK=32, 256 thr (4 waves,
// 64x64/wave). 3-slot LDS ring (48 KB -> 3 blocks/CU resident => 3
// decoupled staging streams per CU). Stage tile t+2 during t; counted
// vmcnt(4) at phase end (never 0 mid-loop). Verified zero-conflict chunk
// swizzle (store src slot u^((row>>1)&3); read slot g^((c>>1)&3)).
// MODE 0: bf16 out.  MODE 1: f32 out = res + v.  MODE 2: bf16 out = swish(v).
template <int MODE>
__global__ __launch_bounds__(256) void gemm_bt(
    const bf16* __restrict__ A, const bf16* __restrict__ WT,
    const float* __restrict__ bias, const float* __restrict__ res,
    void* __restrict__ out, int M, int N, int K) {
  __shared__ bf16 SA[3][128 * 32];  // 24 KiB
  __shared__ bf16 SB[3][128 * 32];  // 24 KiB
  const int t = threadIdx.x;
  const int w = t >> 6, l = t & 63;
  const int wr = w >> 1, wc = w & 1;
  const int c = l & 15, g = l >> 4;
  const long row0 = (long)blockIdx.x * 128;
  const long col0 = (long)blockIdx.y * 128;
  const int NT = K >> 5;

  f32x4 acc[4][4];
#pragma unroll
  for (int m = 0; m < 4; ++m)
#pragma unroll
    for (int n = 0; n < 4; ++n) acc[m][n] = (f32x4){0.f, 0.f, 0.f, 0.f};

  // staging: per wave-instr 16 rows x 64B; lane l -> row l>>2, dest slot l&3,
  // source slot (l&3)^((row>>1)&3) (involution, rule #21)
  const int srow = l >> 2;
  const int sslot = 8 * ((l & 3) ^ ((l >> 3) & 3));
  const bf16* Ag0 = A + (row0 + w * 16 + srow) * (long)K + sslot;
  const bf16* Ag1 = Ag0 + 64 * (long)K;
  const bf16* Bg0 = WT + (col0 + w * 16 + srow) * (long)K + sslot;
  const bf16* Bg1 = Bg0 + 64 * (long)K;
  bf16* const SAf = &SA[0][0];
  bf16* const SBf = &SB[0][0];

#define STAGE(SL, KK)                                            \
  do {                                                           \
    gload16(Ag0 + (KK), SAf + (SL) * 4096 + (w * 16) * 32);      \
    gload16(Ag1 + (KK), SAf + (SL) * 4096 + (64 + w * 16) * 32); \
    gload16(Bg0 + (KK), SBf + (SL) * 4096 + (w * 16) * 32);      \
    gload16(Bg1 + (KK), SBf + (SL) * 4096 + (64 + w * 16) * 32); \
  } while (0)

  // prologue: stage tiles 0,1 (8 loads/wave in flight)
  STAGE(0, 0);
  STAGE(1, 32);

  // read offsets (element units), loop-invariant
  const int rsw = (g ^ ((c >> 1) & 3)) * 8;
  int aoff[4], boff[4];
#pragma unroll
  for (int m = 0; m < 4; ++m) aoff[m] = (wr * 64 + m * 16 + c) * 32 + rsw;
#pragma unroll
  for (int n = 0; n < 4; ++n) boff[n] = (wc * 64 + n * 16 + c) * 32 + rsw;

  asm volatile("s_waitcnt vmcnt(4)" ::: "memory");  // tile 0 landed
  __builtin_amdgcn_s_barrier();

  int cb = 0, sb = 2, kst = 64;
  for (int tt = 0; tt < NT; ++tt) {
    const int ca = cb * 4096;
    bf16x8 af[4], bfr[4];
#pragma unroll
    for (int m = 0; m < 4; ++m) af[m] = *(const bf16x8*)(SAf + ca + aoff[m]);
#pragma unroll
    for (int n = 0; n < 4; ++n) bfr[n] = *(const bf16x8*)(SBf + ca + boff[n]);

    if (tt + 2 < NT) STAGE(sb, kst);

    __builtin_amdgcn_s_barrier();
    asm volatile("s_waitcnt lgkmcnt(0)" ::: "memory");
    __builtin_amdgcn_sched_barrier(0);
    __builtin_amdgcn_s_setprio(1);
#pragma unroll
    for (int m = 0; m < 4; ++m)
#pragma unroll
      for (int n = 0; n < 4; ++n)
        acc[m][n] = __builtin_amdgcn_mfma_f32_16x16x32_bf16(af[m], bfr[n], acc[m][n], 0, 0, 0);
    __builtin_amdgcn_s_setprio(0);

    // wait tile tt+1 (leave tile tt+2's 4 loads in flight)
    if (tt + 2 < NT) {
      asm volatile("s_waitcnt vmcnt(4)" ::: "memory");
    } else {
      asm volatile("s_waitcnt vmcnt(0)" ::: "memory");
    }
    __builtin_amdgcn_s_barrier();

    cb = (cb == 2) ? 0 : cb + 1;
    sb = (sb == 2) ? 0 : sb + 1;
    kst += 32;
  }
#undef STAGE

#pragma unroll
  for (int n = 0; n < 4; ++n) {
    const long col = col0 + wc * 64 + n * 16 + c;
    const float bv = bias[col];
#pragma unroll
    for (int m = 0; m < 4; ++m) {
      const long rowb = row0 + wr * 64 + m * 16 + g * 4;
#pragma unroll
      for (int r = 0; r < 4; ++r) {
        float v = acc[m][n][r] + bv;
        const long idx = (rowb + r) * N + col;
        if (MODE == 0) {
          ((bf16*)out)[idx] = (bf16)v;
        } else if (MODE == 1) {
          ((float*)out)[idx] = res[idx] + v;
        } else {
          float sw = v / (1.f + __expf(-v));
          ((bf16*)out)[idx] = (bf16)sw;
        }
      }
    }
  }
}

// ---- V transpose per head: V [B*S][D] -> VT [B*H][DK][S] ----
__global__ void vtrans(const bf16* __restrict__ V, bf16* __restrict__ VT) {
  __shared__ bf16 tile[32][33];
  int st = blockIdx.x * 32, dt = blockIdx.y * 32;
  int bh = blockIdx.z;
  int b = bh >> 4, h = bh & 15;
  int tx = threadIdx.x, ty = threadIdx.y;
#pragma unroll
  for (int i2 = 0; i2 < 4; ++i2) {
    int i = ty + i2 * 8;
    tile[i][tx] = V[((long)b * NS + st + i) * ND + h * NDK + dt + tx];
  }
  __syncthreads();
#pragma unroll
  for (int i2 = 0; i2 < 4; ++i2) {
    int i = ty + i2 * 8;
    VT[((long)bh * NDK + dt + i) * NS + st + tx] = tile[tx][i];
  }
}

// ---- flash attention v3 (unchanged) ----
__global__ __launch_bounds__(256) void attn_fwd(
    const bf16* __restrict__ Q, const bf16* __restrict__ Kt,
    const bf16* __restrict__ VT, bf16* __restrict__ O) {
  __shared__ bf16 Ks[2][64 * 64];
  __shared__ bf16 Vs[2][64 * 64];
  __shared__ bf16 Pl[4][2][16 * 68];
  int t = threadIdx.x;
  int w = t >> 6, l = t & 63;
  int c = l & 15, g = l >> 4;
  int bid = blockIdx.x;
  int qt = bid >> 7, bh = bid & 127;
  int b = bh >> 4, h = bh & 15;
  int q0 = qt * 128 + w * 32;
  int swz = (c & 7) << 4;

  bf16x8 qf[2][2];
  const bf16* Qbase = Q + (long)(b * NS) * ND + h * NDK;
#pragma unroll
  for (int sj = 0; sj < 2; ++sj) {
    const bf16* qr = Qbase + (long)(q0 + sj * 16 + c) * ND + g * 8;
    qf[sj][0] = *(const bf16x8*)qr;
    qf[sj][1] = *(const bf16x8*)(qr + 32);
  }

  const bf16* Kg = Kt + (long)(b * NS) * ND + h * NDK;
  const bf16* Vg = VT + (long)(b * NH + h) * NDK * NS;

  int sr = l >> 3;
  int sc8 = 8 * ((l & 7) ^ sr);

  f32x4 o[2][4];
#pragma unroll
  for (int sj = 0; sj < 2; ++sj)
#pragma unroll
    for (int ds = 0; ds < 4; ++ds) o[sj][ds] = (f32x4){0.f, 0.f, 0.f, 0.f};
  float mx[2] = {-1e30f, -1e30f};
  float lsum[2] = {0.f, 0.f};

#define STAGE(BUF, KV)                                                        \
  {                                                                           \
    _Pragma("unroll") for (int j = 0; j < 2; ++j) {                           \
      int row = w * 16 + j * 8 + sr;                                          \
      gload16(Kg + (long)((KV) + row) * ND + sc8,                             \
              &Ks[BUF][(w * 16 + j * 8) * 64]);                               \
      gload16(Vg + (long)row * NS + (KV) + sc8,                               \
              &Vs[BUF][(w * 16 + j * 8) * 64]);                               \
    }                                                                         \
  }

  STAGE(0, 0);
  asm volatile("s_waitcnt vmcnt(0)" ::: "memory");
  __syncthreads();

  int buf = 0;
  for (int it = 0; it < NS / 64; ++it) {
    if (it + 1 < NS / 64) STAGE(buf ^ 1, (it + 1) * 64);

    f32x4 sv[2][4];
#pragma unroll
    for (int sj = 0; sj < 2; ++sj)
#pragma unroll
      for (int kt = 0; kt < 4; ++kt) sv[sj][kt] = (f32x4){0.f, 0.f, 0.f, 0.f};
    __builtin_amdgcn_s_setprio(1);
#pragma unroll
    for (int kt = 0; kt < 4; ++kt) {
      const char* kr = (const char*)&Ks[buf][(kt * 16 + c) * 64];
      bf16x8 ka0 = *(const bf16x8*)(kr + ((g * 16) ^ swz));
      bf16x8 ka1 = *(const bf16x8*)(kr + ((64 + g * 16) ^ swz));
#pragma unroll
      for (int sj = 0; sj < 2; ++sj) {
        sv[sj][kt] = __builtin_amdgcn_mfma_f32_16x16x32_bf16(ka0, qf[sj][0], sv[sj][kt], 0, 0, 0);
        sv[sj][kt] = __builtin_amdgcn_mfma_f32_16x16x32_bf16(ka1, qf[sj][1], sv[sj][kt], 0, 0, 0);
      }
    }
    __builtin_amdgcn_s_setprio(0);

    float pm[2];
#pragma unroll
    for (int sj = 0; sj < 2; ++sj) {
      float m = -1e30f;
#pragma unroll
      for (int kt = 0; kt < 4; ++kt)
#pragma unroll
        for (int r = 0; r < 4; ++r) {
          sv[sj][kt][r] *= 0.125f;
          m = fmaxf(m, sv[sj][kt][r]);
        }
      m = fmaxf(m, __shfl_xor(m, 16));
      m = fmaxf(m, __shfl_xor(m, 32));
      pm[sj] = m;
    }
    int cond = (pm[0] <= mx[0] + 8.f) && (pm[1] <= mx[1] + 8.f);
    if (!__all(cond)) {
#pragma unroll
      for (int sj = 0; sj < 2; ++sj) {
        float mn = fmaxf(mx[sj], pm[sj]);
        float sc = __expf(mx[sj] - mn);
        mx[sj] = mn;
        lsum[sj] *= sc;
#pragma unroll
        for (int ds = 0; ds < 4; ++ds)
#pragma unroll
          for (int r = 0; r < 4; ++r) o[sj][ds][r] *= sc;
      }
    }
#pragma unroll
    for (int sj = 0; sj < 2; ++sj) {
      float rs = 0.f;
#pragma unroll
      for (int kt = 0; kt < 4; ++kt) {
        bf16x4 pw;
#pragma unroll
        for (int r = 0; r < 4; ++r) {
          float e = __expf(sv[sj][kt][r] - mx[sj]);
          rs += e;
          pw[r] = (bf16)e;
        }
        *(bf16x4*)&Pl[w][sj][c * 68 + kt * 16 + 4 * g] = pw;
      }
      rs += __shfl_xor(rs, 16);
      rs += __shfl_xor(rs, 32);
      lsum[sj] += rs;
    }
    asm volatile("s_waitcnt lgkmcnt(0)" ::: "memory");
    __builtin_amdgcn_sched_barrier(0);

    __builtin_amdgcn_s_setprio(1);
#pragma unroll
    for (int ks = 0; ks < 2; ++ks) {
      bf16x8 pb0 = *(const bf16x8*)&Pl[w][0][c * 68 + ks * 32 + g * 8];
      bf16x8 pb1 = *(const bf16x8*)&Pl[w][1][c * 68 + ks * 32 + g * 8];
#pragma unroll
      for (int ds = 0; ds < 4; ++ds) {
        const char* vr = (const char*)&Vs[buf][(ds * 16 + c) * 64];
        bf16x8 va = *(const bf16x8*)(vr + ((ks * 64 + g * 16) ^ swz));
        o[0][ds] = __builtin_amdgcn_mfma_f32_16x16x32_bf16(va, pb0, o[0][ds], 0, 0, 0);
        o[1][ds] = __builtin_amdgcn_mfma_f32_16x16x32_bf16(va, pb1, o[1][ds], 0, 0, 0);
      }
    }
    __builtin_amdgcn_s_setprio(0);
    __syncthreads();
    buf ^= 1;
  }

#pragma unroll
  for (int sj = 0; sj < 2; ++sj) {
    float inv = 1.f / lsum[sj];
    bf16* Orow = O + (long)(b * NS + q0 + sj * 16 + c) * ND + h * NDK;
#pragma unroll
    for (int ds = 0; ds < 4; ++ds) {
      bf16x4 ov;
#pragma unroll
      for (int r = 0; r < 4; ++r) ov[r] = (bf16)(o[sj][ds][r] * inv);
      *(bf16x4*)(Orow + ds * 16 + 4 * g) = ov;
    }
  }
#undef STAGE
}

extern "C" void kernel_launch(void* const* d_in, const int* in_sizes, int n_in,
                              void* d_out, int out_size, void* d_ws, size_t ws_size,
                              hipStream_t stream) {
  (void)in_sizes; (void)n_in; (void)out_size; (void)ws_size;
  const float* x = (const float*)d_in[0];
  const float* y = (const float*)d_in[1];
  const float* x_pos = (const float*)d_in[2];
  const float* y_pos = (const float*)d_in[3];

  char* ws = (char*)d_ws;
  const size_t MB = 1ull << 20;
  bf16* Wt[8];
  for (int i = 0; i < 8; ++i) Wt[i] = (bf16*)(ws + (size_t)i * 2 * MB);
  bf16* W1T = (bf16*)(ws + 16 * MB);
  bf16* W2T = (bf16*)(ws + 24 * MB);
  float* xres = (float*)(ws + 32 * MB);
  bf16* x2 = (bf16*)(ws + 64 * MB);
  bf16* qk = (bf16*)(ws + 80 * MB);
  bf16* y2 = (bf16*)(ws + 96 * MB);
  bf16* yk = (bf16*)(ws + 112 * MB);
  bf16* Qb = (bf16*)(ws + 128 * MB);
  bf16* Kb = (bf16*)(ws + 144 * MB);
  bf16* Vb = (bf16*)(ws + 160 * MB);
  bf16* VTb = (bf16*)(ws + 176 * MB);
  bf16* Ob = (bf16*)(ws + 192 * MB);
  bf16* hb = (bf16*)(ws + 128 * MB);  // aliases Qb..VTb (free during FFN)

  dim3 tb(32, 8);
  for (int i = 0; i < 8; ++i)
    wconv_t<<<dim3(32, 32), tb, 0, stream>>>((const float*)d_in[4 + 2 * i], Wt[i], 1024, 1024);
  wconv_t<<<dim3(128, 32), tb, 0, stream>>>((const float*)d_in[20], W1T, 1024, 4096);
  wconv_t<<<dim3(32, 128), tb, 0, stream>>>((const float*)d_in[22], W2T, 4096, 1024);

  const float* ln1g = (const float*)d_in[24]; const float* ln1b = (const float*)d_in[25];
  const float* ln2g = (const float*)d_in[26]; const float* ln2b = (const float*)d_in[27];
  const float* ln3g = (const float*)d_in[28]; const float* ln3b = (const float*)d_in[29];
  const float* ln4g = (const float*)d_in[30]; const float* ln4b = (const float*)d_in[31];

  dim3 gD(64, 8);     // M-tiles(128) x N-tiles(128)
  dim3 gF1(64, 32);
  dim3 gVT(32, 2, 128);

  // ---- self-attention ----
  ln_fused<<<8192, 256, 0, stream>>>(x, ln1g, ln1b, x_pos, x2, qk);
  gemm_bt<0><<<gD, 256, 0, stream>>>(qk, Wt[0], (const float*)d_in[5], nullptr, Qb, 8192, 1024, 1024);
  gemm_bt<0><<<gD, 256, 0, stream>>>(qk, Wt[1], (const float*)d_in[7], nullptr, Kb, 8192, 1024, 1024);
  gemm_bt<0><<<gD, 256, 0, stream>>>(x2, Wt[2], (const float*)d_in[9], nullptr, Vb, 8192, 1024, 1024);
  vtrans<<<gVT, tb, 0, stream>>>(Vb, VTb);
  attn_fwd<<<1024, 256, 0, stream>>>(Qb, Kb, VTb, Ob);
  gemm_bt<1><<<gD, 256, 0, stream>>>(Ob, Wt[3], (const float*)d_in[11], x, xres, 8192, 1024, 1024);

  // ---- cross-attention ----
  ln_fused<<<8192, 256, 0, stream>>>(xres, ln2g, ln2b, x_pos, nullptr, qk);
  ln_fused<<<8192, 256, 0, stream>>>(y, ln3g, ln3b, y_pos, y2, yk);
  gemm_bt<0><<<gD, 256, 0, stream>>>(qk, Wt[4], (const float*)d_in[13], nullptr, Qb, 8192, 1024, 1024);
  gemm_bt<0><<<gD, 256, 0, stream>>>(yk, Wt[5], (const float*)d_in[15], nullptr, Kb, 8192, 1024, 1024);
  gemm_bt<0><<<gD, 256, 0, stream>>>(y2, Wt[6], (const float*)d_in[17], nullptr, Vb, 8192, 1024, 1024);
  vtrans<<<gVT, tb, 0, stream>>>(Vb, VTb);
  attn_fwd<<<1024, 256, 0, stream>>>(Qb, Kb, VTb, Ob);
  gemm_bt<1><<<gD, 256, 0, stream>>>(Ob, Wt[7], (const float*)d_in[19], xres, xres, 8192, 1024, 1024);

  // ---- FFN ----
  ln_fused<<<8192, 256, 0, stream>>>(xres, ln4g, ln4b, nullptr, x2, nullptr);
  gemm_bt<2><<<gF1, 256, 0, stream>>>(x2, W1T, (const float*)d_in[21], nullptr, hb, 8192, 4096, 1024);
  gemm_bt<1><<<gD, 256, 0, stream>>>(hb, W2T, (const float*)d_in[23], xres, (float*)d_out, 8192, 1024, 4096);
}